// Round 19
// baseline (605.340 us; speedup 1.0000x reference)
//
#include <hip/hip_runtime.h>
#include <hip/hip_fp16.h>
#include <cstddef>

#define N_NODES  100000
#define N_EDGES  640000
#define WIDTH    128
#define LAYERS   3
#define N_GRAPHS 64
#define ELL_K    40
#define YN       4                       // nodes per wave in yagg
#define YBLK     (N_NODES / 16)          // 6250 blocks (16 nodes/block), exact

#define GLOAD_LDS16(gsrc, ldst) \
  __builtin_amdgcn_global_load_lds( \
      (const __attribute__((address_space(1))) unsigned*)(gsrc), \
      (__attribute__((address_space(3))) unsigned*)(ldst), 16, 0, 0)

__device__ __forceinline__ float h2f(unsigned short h) {
  __half x; *reinterpret_cast<unsigned short*>(&x) = h;
  return __half2float(x);
}
__device__ __forceinline__ unsigned short f2h(float f) {
  __half h = __float2half_rn(f);
  return *reinterpret_cast<unsigned short*>(&h);
}

// ---------------- setup kernels ----------------

__global__ void k_init(int* __restrict__ cursor, float* __restrict__ deg) {
  int i = blockIdx.x * blockDim.x + threadIdx.x;
  if (i < N_NODES) { cursor[i] = 0; deg[i] = 0.f; }
}

// merged edge pass: weighted in-degree + ELL fill with RAW edge weight
__global__ void k_fill_cd(const int* __restrict__ row, const int* __restrict__ col,
                          const float* __restrict__ ew,
                          int* __restrict__ cursor, float* __restrict__ deg,
                          int2* __restrict__ ell) {
  int e = blockIdx.x * blockDim.x + threadIdx.x;
  if (e < N_EDGES) {
    int r = row[e], c = col[e];
    float w = ew[e];
    atomicAdd(&deg[c], w);
    int slot = atomicAdd(&cursor[r], 1);
    if (slot < ELL_K) {
      int2 pk; pk.x = c; pk.y = __float_as_int(w);
      ell[(size_t)r * ELL_K + slot] = pk;
    }
  }
}

// elementwise: dinv = rsqrt(d), d2 = 1/d, sq = sqrt(d)
__global__ void k_dinv_e(const float* __restrict__ deg, float* __restrict__ dinv,
                         float* __restrict__ d2, float* __restrict__ sq) {
  int v = blockIdx.x * blockDim.x + threadIdx.x;
  if (v < N_NODES) {
    float d = 2.0f + deg[v];
    float di = (d > 0.0f) ? 1.0f / sqrtf(d) : 0.0f;
    dinv[v] = di;
    d2[v] = di * di;
    sq[v] = sqrtf(d);
  }
}

__device__ __forceinline__ int lbound(const int* __restrict__ batch, int key) {
  int lo = 0, hi = N_NODES;
  while (lo < hi) { int m = (lo + hi) >> 1; if (batch[m] < key) lo = m + 1; else hi = m; }
  return lo;
}

// per-graph counts + 1/max(cnt,1)
__global__ void k_cntg(const int* __restrict__ batch, int* __restrict__ cntg,
                       float* __restrict__ invc) {
  int g = threadIdx.x;
  if (g < N_GRAPHS) {
    int lb = lbound(batch, g), ub = lbound(batch, g + 1);
    int c = ub - lb;
    cntg[g] = c;
    invc[g] = 1.0f / (float)max(c, 1);
  }
}

// z0[v][g] = (batch[v]==g) * invc[g] * dinv[v]   (z-space P^T, N x 64 fp16)
__global__ void k_pinit(const int* __restrict__ batch, const float* __restrict__ invc,
                        const float* __restrict__ dinv, unsigned short* __restrict__ p) {
  const int total = N_NODES * 16;   // ushort4 count
  for (int i = blockIdx.x * blockDim.x + threadIdx.x; i < total;
       i += gridDim.x * blockDim.x) {
    int v = i >> 4, q = i & 15;
    int b = batch[v];
    unsigned short val = f2h(invc[b] * dinv[v]);
    ushort4 u;
    ((unsigned short*)&u)[0] = (q * 4 + 0 == b) ? val : (unsigned short)0;
    ((unsigned short*)&u)[1] = (q * 4 + 1 == b) ? val : (unsigned short)0;
    ((unsigned short*)&u)[2] = (q * 4 + 2 == b) ? val : (unsigned short)0;
    ((unsigned short*)&u)[3] = (q * 4 + 3 == b) ? val : (unsigned short)0;
    ((ushort4*)p)[i] = u;
  }
}

// reduce colsum partials (YBLK rows): block 0 -> ps (csA), block 1 -> pas (csB)
__global__ __launch_bounds__(256) void k_cs2(
    const float* __restrict__ csA, const float* __restrict__ csB,
    float* __restrict__ ps, float* __restrict__ pas) {
  __shared__ float sd[256];
  const float* src = (blockIdx.x == 0) ? csA : csB;
  float* dst = (blockIdx.x == 0) ? ps : pas;
  int t = threadIdx.x;
  int g = t & 63, c = t >> 6;   // 4 interleaved row-chunks
  float a = 0.f;
  for (int r = c; r < YBLK; r += 4) a += src[(size_t)r * 64 + g];
  sd[t] = a;
  __syncthreads();
  if (t < 128) sd[t] += sd[t + 128];
  __syncthreads();
  if (t < 64) dst[t] = sd[t] + sd[t + 64];
}

// ---------------- y-chain (z-space): zout = scale * (sum w*z[col] + 2*zin) ----------------
// v2: FOUR nodes per wave, all ELL/self loads issued up front (4 independent
// latency chains in flight). Optional fused sq-weighted colsum -> partc[block].
__global__ __launch_bounds__(256) void k_yagg(
    const unsigned short* __restrict__ yin, const int* __restrict__ cnt_a,
    const int2* __restrict__ ell, const float* __restrict__ scale,
    const float* __restrict__ sq, unsigned short* __restrict__ yout,
    float* __restrict__ partc) {
  __shared__ float4 sdc[4][16];
  int wave = threadIdx.x >> 6;
  int lane = threadIdx.x & 63;
  int base = (blockIdx.x * 4 + wave) * YN;   // exact fit: no guards needed
  int grp = lane >> 4;    // 0..3 edge group
  int q = lane & 15;      // ushort4 slot

  // ---- load phase: 4 nodes' ELL rows + self rows all in flight ----
  int cnt[YN]; int2 pk[YN]; ushort4 hvu[YN];
#pragma unroll
  for (int i = 0; i < YN; i++) {
    int v = base + i;
    cnt[i] = cnt_a[v];
    pk[i] = (lane < cnt[i]) ? ell[(size_t)v * ELL_K + lane] : make_int2(0, 0);
    hvu[i] = ((const ushort4*)(yin + (size_t)v * 64))[q];
  }

  float4 cs = {0.f, 0.f, 0.f, 0.f};
#pragma unroll
  for (int i = 0; i < YN; i++) {
    int v = base + i;
    int cn = cnt[i];
    int si = pk[i].x;
    float swv = __int_as_float(pk[i].y);
    float4 a0 = {0,0,0,0}, a1 = {0,0,0,0}, a2 = {0,0,0,0}, a3 = {0,0,0,0};

    for (int b = 0; b < cn; b += 16) {
      int e0 = b + grp;
      float w0 = __shfl(swv, e0); int i0 = __shfl(si, e0);
      ushort4 u0 = ((const ushort4*)(yin + (size_t)i0 * 64))[q];
      a0.x += w0 * h2f(u0.x); a0.y += w0 * h2f(u0.y);
      a0.z += w0 * h2f(u0.z); a0.w += w0 * h2f(u0.w);
      if (b + 4 < cn) {
        int e1 = b + 4 + grp;
        float w1 = __shfl(swv, e1); int i1 = __shfl(si, e1);
        ushort4 u1 = ((const ushort4*)(yin + (size_t)i1 * 64))[q];
        a1.x += w1 * h2f(u1.x); a1.y += w1 * h2f(u1.y);
        a1.z += w1 * h2f(u1.z); a1.w += w1 * h2f(u1.w);
      }
      if (b + 8 < cn) {
        int e2 = b + 8 + grp;
        int e3 = b + 12 + grp;
        float w2 = __shfl(swv, e2); int i2 = __shfl(si, e2);
        float w3 = __shfl(swv, e3); int i3 = __shfl(si, e3);
        ushort4 u2 = ((const ushort4*)(yin + (size_t)i2 * 64))[q];
        ushort4 u3 = ((const ushort4*)(yin + (size_t)i3 * 64))[q];
        a2.x += w2 * h2f(u2.x); a2.y += w2 * h2f(u2.y);
        a2.z += w2 * h2f(u2.z); a2.w += w2 * h2f(u2.w);
        a3.x += w3 * h2f(u3.x); a3.y += w3 * h2f(u3.y);
        a3.z += w3 * h2f(u3.z); a3.w += w3 * h2f(u3.w);
      }
    }

    a0.x += a1.x + a2.x + a3.x;
    a0.y += a1.y + a2.y + a3.y;
    a0.z += a1.z + a2.z + a3.z;
    a0.w += a1.w + a2.w + a3.w;
#pragma unroll
    for (int d = 16; d <= 32; d <<= 1) {
      a0.x += __shfl_xor(a0.x, d);
      a0.y += __shfl_xor(a0.y, d);
      a0.z += __shfl_xor(a0.z, d);
      a0.w += __shfl_xor(a0.w, d);
    }

    if (grp == 0) {
      float sc = scale[v];
      float rx = sc * (a0.x + 2.0f * h2f(hvu[i].x));
      float ry = sc * (a0.y + 2.0f * h2f(hvu[i].y));
      float rz = sc * (a0.z + 2.0f * h2f(hvu[i].z));
      float rw = sc * (a0.w + 2.0f * h2f(hvu[i].w));
      ushort4 r;
      r.x = f2h(rx); r.y = f2h(ry); r.z = f2h(rz); r.w = f2h(rw);
      ((ushort4*)(yout + (size_t)v * 64))[q] = r;
      if (partc) {
        float wv = sq[v];
        cs.x += wv * rx; cs.y += wv * ry;
        cs.z += wv * rz; cs.w += wv * rw;
      }
    }
  }

  if (partc) {
    if (grp == 0) sdc[wave][q] = cs;
    __syncthreads();
    if (threadIdx.x < 16) {
      int qq = threadIdx.x;
      float4 a = sdc[0][qq], b = sdc[1][qq], c = sdc[2][qq], d = sdc[3][qq];
      a.x += b.x + c.x + d.x;
      a.y += b.y + c.y + d.y;
      a.z += b.z + c.z + d.z;
      a.w += b.w + c.w + d.w;
      ((float4*)(partc + (size_t)blockIdx.x * 64))[qq] = a;
    }
  }
}

// ---------------- contraction v4 (r18): LDS-staged, slab-level conversion ----------------
#define CT_BLOCKS 768
#define CT_NCHUNK ((N_NODES + 63) / 64)   // 1563

__global__ __launch_bounds__(256) void k_contract(
    const float* __restrict__ x0, const unsigned short* __restrict__ y3,
    float* __restrict__ part) {
  __shared__ __align__(16) float xs[64 * 128];   // 32 KB
  __shared__ __align__(16) float ysf[64 * 64];   // 16 KB converted f32
  int t = threadIdx.x;
  int w = t >> 6;
  int lane = t & 63;
  int j = lane * 2;

  float2 acc[16];
#pragma unroll
  for (int i = 0; i < 16; i++) acc[i] = make_float2(0.f, 0.f);

  for (int c = blockIdx.x; c < CT_NCHUNK; c += gridDim.x) {
    int cc = min(64, N_NODES - c * 64);
    int bx = cc * 512;
    int byh = cc * 128;
    const char* gx = (const char*)(x0 + (size_t)c * 64 * 128);
    const char* gy = (const char*)(y3 + (size_t)c * 64 * 64);
    __syncthreads();
#pragma unroll
    for (int i = 0; i < 8; i++) {
      int off = i * 4096 + t * 16;
      if (off < bx) GLOAD_LDS16(gx + off, (char*)xs + off);
    }
    ushort4 u[4];
#pragma unroll
    for (int r = 0; r < 4; r++) {
      int off = (r * 256 + t) * 8;
      u[r] = (off < byh) ? *(const ushort4*)(gy + off)
                         : make_ushort4(0, 0, 0, 0);
    }
#pragma unroll
    for (int r = 0; r < 4; r++) {
      int idx = (r * 256 + t) * 4;
      if (idx < cc * 64)
        *(float4*)(ysf + idx) = make_float4(h2f(u[r].x), h2f(u[r].y),
                                            h2f(u[r].z), h2f(u[r].w));
    }
    asm volatile("s_waitcnt vmcnt(0)" ::: "memory");
    __syncthreads();

    int v = 0;
    for (; v + 2 <= cc; v += 2) {
      float2 xa = *(const float2*)(xs + v * 128 + j);
      float2 xb = *(const float2*)(xs + (v + 1) * 128 + j);
      const float4* ya = (const float4*)(ysf + v * 64 + w * 16);
      const float4* yb = (const float4*)(ysf + (v + 1) * 64 + w * 16);
      float4 a0 = ya[0], a1 = ya[1], a2 = ya[2], a3 = ya[3];
      float4 b0 = yb[0], b1 = yb[1], b2 = yb[2], b3 = yb[3];
      float yas[16] = {a0.x, a0.y, a0.z, a0.w, a1.x, a1.y, a1.z, a1.w,
                       a2.x, a2.y, a2.z, a2.w, a3.x, a3.y, a3.z, a3.w};
      float ybs[16] = {b0.x, b0.y, b0.z, b0.w, b1.x, b1.y, b1.z, b1.w,
                       b2.x, b2.y, b2.z, b2.w, b3.x, b3.y, b3.z, b3.w};
#pragma unroll
      for (int i = 0; i < 16; i++) {
        acc[i].x += yas[i] * xa.x;
        acc[i].y += yas[i] * xa.y;
      }
#pragma unroll
      for (int i = 0; i < 16; i++) {
        acc[i].x += ybs[i] * xb.x;
        acc[i].y += ybs[i] * xb.y;
      }
    }
    if (v < cc) {
      float2 xa = *(const float2*)(xs + v * 128 + j);
      const float4* ya = (const float4*)(ysf + v * 64 + w * 16);
      float4 a0 = ya[0], a1 = ya[1], a2 = ya[2], a3 = ya[3];
      float yas[16] = {a0.x, a0.y, a0.z, a0.w, a1.x, a1.y, a1.z, a1.w,
                       a2.x, a2.y, a2.z, a2.w, a3.x, a3.y, a3.z, a3.w};
#pragma unroll
      for (int i = 0; i < 16; i++) {
        acc[i].x += yas[i] * xa.x;
        acc[i].y += yas[i] * xa.y;
      }
    }
  }

  float* dst = part + (size_t)blockIdx.x * (N_GRAPHS * WIDTH);
#pragma unroll
  for (int i = 0; i < 16; i++)
    *(float2*)(dst + (w * 16 + i) * WIDTH + j) = acc[i];
}

// ---------------- partials reduction: 768 rows -> 12 rows ----------------
#define RC_ROWS 64
#define RC_RG (CT_BLOCKS / RC_ROWS)   // 12

__global__ __launch_bounds__(256) void k_reduce1(
    const float* __restrict__ part, float* __restrict__ part2) {
  int bid = blockIdx.x, t = threadIdx.x;
  int rg = bid >> 5, colc = bid & 31;
  int idx = colc * 256 + t;
  const float* src = part + (size_t)rg * RC_ROWS * (N_GRAPHS * WIDTH) + idx;
  float a0 = 0.f, a1 = 0.f, a2 = 0.f, a3 = 0.f;
  for (int r = 0; r < RC_ROWS; r += 4) {
    a0 += src[(size_t)(r + 0) * (N_GRAPHS * WIDTH)];
    a1 += src[(size_t)(r + 1) * (N_GRAPHS * WIDTH)];
    a2 += src[(size_t)(r + 2) * (N_GRAPHS * WIDTH)];
    a3 += src[(size_t)(r + 3) * (N_GRAPHS * WIDTH)];
  }
  part2[rg * (N_GRAPHS * WIDTH) + idx] = (a0 + a1) + (a2 + a3);
}

// O = A*B (128x128 f32); block=row, thread=col
__global__ __launch_bounds__(WIDTH) void k_mm128(
    const float* __restrict__ A, const float* __restrict__ B, float* __restrict__ O) {
  __shared__ float Ar[WIDTH];
  int r = blockIdx.x, j = threadIdx.x;
  Ar[j] = A[r * WIDTH + j];
  __syncthreads();
  float a = 0.f;
#pragma unroll 8
  for (int k = 0; k < WIDTH; k++) a += Ar[k] * B[k * WIDTH + j];
  O[r * WIDTH + j] = a;
}

// c0 = b0^T * T1 ; c1 = b1^T * W2
__global__ __launch_bounds__(WIDTH) void k_c01(
    const float* __restrict__ b0, const float* __restrict__ T1,
    const float* __restrict__ b1, const float* __restrict__ W2,
    float* __restrict__ c0, float* __restrict__ c1) {
  __shared__ float s0[WIDTH], s1v[WIDTH];
  int j = threadIdx.x;
  s0[j] = b0[j]; s1v[j] = b1[j];
  __syncthreads();
  float a0 = 0.f, a1 = 0.f;
#pragma unroll 8
  for (int k = 0; k < WIDTH; k++) {
    a0 += s0[k] * T1[k * WIDTH + j];
    a1 += s1v[k] * W2[k * WIDTH + j];
  }
  c0[j] = a0; c1[j] = a1;
}

// out[g][j]: final 12-row C-sum fused in.
__global__ __launch_bounds__(WIDTH) void k_out(
    const float* __restrict__ part2, const float* __restrict__ Wp,
    const float* __restrict__ c0, const float* __restrict__ c1,
    const float* __restrict__ ps, const float* __restrict__ pas,
    const int* __restrict__ cntg, const float* __restrict__ b2,
    float* __restrict__ out) {
  __shared__ float Cr[WIDTH];
  int g = blockIdx.x, j = threadIdx.x;
  float cv = 0.f;
#pragma unroll
  for (int rg = 0; rg < RC_RG; rg++)
    cv += part2[rg * (N_GRAPHS * WIDTH) + g * WIDTH + j];
  Cr[j] = cv;
  __syncthreads();
  float a = pas[g] * c0[j] + ps[g] * c1[j] + ((cntg[g] > 0) ? b2[j] : 0.f);
#pragma unroll 8
  for (int k = 0; k < WIDTH; k++) a += Cr[k] * Wp[k * WIDTH + j];
  out[g * WIDTH + j] = a;
}

// ---------------- launch ----------------

extern "C" void kernel_launch(void* const* d_in, const int* in_sizes, int n_in,
                              void* d_out, int out_size, void* d_ws, size_t ws_size,
                              hipStream_t stream) {
  const float* x   = (const float*)d_in[0];
  const int* row   = (const int*)d_in[1];         // edge_index[0]
  const int* col   = row + N_EDGES;               // edge_index[1]
  const float* ew  = (const float*)d_in[2];
  const int* batch = (const int*)d_in[3];
  const float* Ws  = (const float*)d_in[4];
  const float* bs  = (const float*)d_in[5];
  float* out = (float*)d_out;

  char* w = (char*)d_ws;
  float* dinv    = (float*)(w + 0);
  float* d2      = (float*)(w + 400128);
  float* sq      = (float*)(w + 800256);
  float* deg     = (float*)(w + 1200384);
  int*   cursor  = (int*)(w + 1600512);
  int*   cntg    = (int*)(w + 2000640);
  float* invc    = (float*)(w + 2000896);
  float* ps      = (float*)(w + 2001152);
  float* pas     = (float*)(w + 2001408);
  float* T1      = (float*)(w + 2001664);
  float* Wp      = (float*)(w + 2067200);
  float* c0      = (float*)(w + 2132736);
  float* c1      = (float*)(w + 2133248);
  int2*  ell     = (int2*)(w + 2133760);     // 32 MB -> ends 34133760
  float* part    = (float*)(w + 34133760);   // 768*8192*4 = 25.2 MB
  float* part2   = (float*)(w + 67688192);   // 12*8192*4
  unsigned short* yA = (unsigned short*)(w + 68212480);  // N*64 fp16
  unsigned short* yB = (unsigned short*)(w + 81012480);  // N*64 fp16, ends 93812480
  float* csA     = (float*)(w + 93812480);   // 6250*64 f32 = 1.6MB
  float* csB     = (float*)(w + 95412480);   // ends 97012480

  int nb_n = (N_NODES + 255) / 256;
  int nb_e = (N_EDGES + 255) / 256;

  k_init   <<<nb_n, 256, 0, stream>>>(cursor, deg);
  k_fill_cd<<<nb_e, 256, 0, stream>>>(row, col, ew, cursor, deg, ell);
  k_dinv_e <<<nb_n, 256, 0, stream>>>(deg, dinv, d2, sq);

  k_cntg <<<1, 64, 0, stream>>>(batch, cntg, invc);
  k_pinit<<<2048, 256, 0, stream>>>(batch, invc, dinv, yA);

  k_yagg<<<YBLK, 256, 0, stream>>>(yA, cursor, ell, d2, sq, yB, csA);      // z1 (+ps)
  k_yagg<<<YBLK, 256, 0, stream>>>(yB, cursor, ell, d2, sq, yA, csB);      // z2 (+pas)
  k_yagg<<<YBLK, 256, 0, stream>>>(yA, cursor, ell, dinv, sq, yB, nullptr);// y3

  k_cs2  <<<2, 256, 0, stream>>>(csA, csB, ps, pas);
  k_mm128<<<WIDTH, WIDTH, 0, stream>>>(Ws + 1 * WIDTH * WIDTH, Ws + 2 * WIDTH * WIDTH, T1);
  k_mm128<<<WIDTH, WIDTH, 0, stream>>>(Ws + 0 * WIDTH * WIDTH, T1, Wp);
  k_c01  <<<1, WIDTH, 0, stream>>>(bs, T1, bs + WIDTH, Ws + 2 * WIDTH * WIDTH, c0, c1);

  k_contract<<<CT_BLOCKS, 256, 0, stream>>>(x, yB, part);
  k_reduce1 <<<RC_RG * 32, 256, 0, stream>>>(part, part2);
  k_out     <<<N_GRAPHS, WIDTH, 0, stream>>>(part2, Wp, c0, c1, ps, pas, cntg,
                                             bs + 2 * WIDTH, out);
}

// Round 20
// 249.828 us; speedup vs baseline: 2.4230x; 2.4230x over previous
//
#include <hip/hip_runtime.h>
#include <hip/hip_fp16.h>
#include <cstddef>

#define N_NODES  100000
#define N_EDGES  640000
#define WIDTH    128
#define LAYERS   3
#define N_GRAPHS 64
#define ELL_K    40
#define YN       4                       // nodes per wave in yagg
#define YBLK     (N_NODES / 16)          // 6250 blocks (16 nodes/block), exact

#define GLOAD_LDS16(gsrc, ldst) \
  __builtin_amdgcn_global_load_lds( \
      (const __attribute__((address_space(1))) unsigned*)(gsrc), \
      (__attribute__((address_space(3))) unsigned*)(ldst), 16, 0, 0)

__device__ __forceinline__ float h2f(unsigned short h) {
  __half x; *reinterpret_cast<unsigned short*>(&x) = h;
  return __half2float(x);
}
__device__ __forceinline__ unsigned short f2h(float f) {
  __half h = __float2half_rn(f);
  return *reinterpret_cast<unsigned short*>(&h);
}

// ---------------- setup kernels ----------------

__global__ void k_init(int* __restrict__ cursor, float* __restrict__ deg) {
  int i = blockIdx.x * blockDim.x + threadIdx.x;
  if (i < N_NODES) { cursor[i] = 0; deg[i] = 0.f; }
}

// merged edge pass: weighted in-degree + ELL fill with RAW edge weight
__global__ void k_fill_cd(const int* __restrict__ row, const int* __restrict__ col,
                          const float* __restrict__ ew,
                          int* __restrict__ cursor, float* __restrict__ deg,
                          int2* __restrict__ ell) {
  int e = blockIdx.x * blockDim.x + threadIdx.x;
  if (e < N_EDGES) {
    int r = row[e], c = col[e];
    float w = ew[e];
    atomicAdd(&deg[c], w);
    int slot = atomicAdd(&cursor[r], 1);
    if (slot < ELL_K) {
      int2 pk; pk.x = c; pk.y = __float_as_int(w);
      ell[(size_t)r * ELL_K + slot] = pk;
    }
  }
}

// elementwise: dinv = rsqrt(d), d2 = 1/d, sq = sqrt(d)
__global__ void k_dinv_e(const float* __restrict__ deg, float* __restrict__ dinv,
                         float* __restrict__ d2, float* __restrict__ sq) {
  int v = blockIdx.x * blockDim.x + threadIdx.x;
  if (v < N_NODES) {
    float d = 2.0f + deg[v];
    float di = (d > 0.0f) ? 1.0f / sqrtf(d) : 0.0f;
    dinv[v] = di;
    d2[v] = di * di;
    sq[v] = sqrtf(d);
  }
}

__device__ __forceinline__ int lbound(const int* __restrict__ batch, int key) {
  int lo = 0, hi = N_NODES;
  while (lo < hi) { int m = (lo + hi) >> 1; if (batch[m] < key) lo = m + 1; else hi = m; }
  return lo;
}

// per-graph counts + 1/max(cnt,1)
__global__ void k_cntg(const int* __restrict__ batch, int* __restrict__ cntg,
                       float* __restrict__ invc) {
  int g = threadIdx.x;
  if (g < N_GRAPHS) {
    int lb = lbound(batch, g), ub = lbound(batch, g + 1);
    int c = ub - lb;
    cntg[g] = c;
    invc[g] = 1.0f / (float)max(c, 1);
  }
}

// z0[v][g] = (batch[v]==g) * invc[g] * dinv[v]   (z-space P^T, N x 64 fp16)
__global__ void k_pinit(const int* __restrict__ batch, const float* __restrict__ invc,
                        const float* __restrict__ dinv, unsigned short* __restrict__ p) {
  const int total = N_NODES * 16;   // ushort4 count
  for (int i = blockIdx.x * blockDim.x + threadIdx.x; i < total;
       i += gridDim.x * blockDim.x) {
    int v = i >> 4, q = i & 15;
    int b = batch[v];
    unsigned short val = f2h(invc[b] * dinv[v]);
    ushort4 u;
    ((unsigned short*)&u)[0] = (q * 4 + 0 == b) ? val : (unsigned short)0;
    ((unsigned short*)&u)[1] = (q * 4 + 1 == b) ? val : (unsigned short)0;
    ((unsigned short*)&u)[2] = (q * 4 + 2 == b) ? val : (unsigned short)0;
    ((unsigned short*)&u)[3] = (q * 4 + 3 == b) ? val : (unsigned short)0;
    ((ushort4*)p)[i] = u;
  }
}

// stage-1 reduce of colsum partials: 2 buffers x 64 chunks of ~98 rows.
// coalesced float4 reads (16 slots x 16 rows layout), LDS tree, 1 row out.
#define CSR_CHUNK ((YBLK + 63) / 64)   // 98
__global__ __launch_bounds__(256) void k_csr(
    const float* __restrict__ csA, const float* __restrict__ csB,
    float* __restrict__ part3) {
  __shared__ float4 sd[256];
  int buf = blockIdx.x >> 6;
  int chunk = blockIdx.x & 63;
  const float* src = buf ? csB : csA;
  int t = threadIdx.x;
  int slot = t & 15;      // float4 slot within 64-float row
  int vr = t >> 4;        // 16 rows in flight
  int start = chunk * CSR_CHUNK;
  int end = min(start + CSR_CHUNK, YBLK);
  float4 acc = {0.f, 0.f, 0.f, 0.f};
  for (int r = start + vr; r < end; r += 16) {
    float4 v = ((const float4*)(src + (size_t)r * 64))[slot];
    acc.x += v.x; acc.y += v.y; acc.z += v.z; acc.w += v.w;
  }
  sd[t] = acc;
  __syncthreads();
  for (int off = 8; off > 0; off >>= 1) {
    if (vr < off) {
      float4 o = sd[(vr + off) * 16 + slot];
      acc.x += o.x; acc.y += o.y; acc.z += o.z; acc.w += o.w;
      sd[t] = acc;
    }
    __syncthreads();
  }
  if (vr == 0)
    ((float4*)(part3 + ((size_t)buf * 64 + chunk) * 64))[slot] = acc;
}

// ---------------- y-chain (z-space): zout = scale * (sum w*z[col] + 2*zin) ----------------
// FOUR nodes per wave, loads issued up front; optional fused sq-weighted colsum.
__global__ __launch_bounds__(256) void k_yagg(
    const unsigned short* __restrict__ yin, const int* __restrict__ cnt_a,
    const int2* __restrict__ ell, const float* __restrict__ scale,
    const float* __restrict__ sq, unsigned short* __restrict__ yout,
    float* __restrict__ partc) {
  __shared__ float4 sdc[4][16];
  int wave = threadIdx.x >> 6;
  int lane = threadIdx.x & 63;
  int base = (blockIdx.x * 4 + wave) * YN;   // exact fit: no guards needed
  int grp = lane >> 4;    // 0..3 edge group
  int q = lane & 15;      // ushort4 slot

  int cnt[YN]; int2 pk[YN]; ushort4 hvu[YN];
#pragma unroll
  for (int i = 0; i < YN; i++) {
    int v = base + i;
    cnt[i] = cnt_a[v];
    pk[i] = (lane < cnt[i]) ? ell[(size_t)v * ELL_K + lane] : make_int2(0, 0);
    hvu[i] = ((const ushort4*)(yin + (size_t)v * 64))[q];
  }

  float4 cs = {0.f, 0.f, 0.f, 0.f};
#pragma unroll
  for (int i = 0; i < YN; i++) {
    int v = base + i;
    int cn = cnt[i];
    int si = pk[i].x;
    float swv = __int_as_float(pk[i].y);
    float4 a0 = {0,0,0,0}, a1 = {0,0,0,0}, a2 = {0,0,0,0}, a3 = {0,0,0,0};

    for (int b = 0; b < cn; b += 16) {
      int e0 = b + grp;
      float w0 = __shfl(swv, e0); int i0 = __shfl(si, e0);
      ushort4 u0 = ((const ushort4*)(yin + (size_t)i0 * 64))[q];
      a0.x += w0 * h2f(u0.x); a0.y += w0 * h2f(u0.y);
      a0.z += w0 * h2f(u0.z); a0.w += w0 * h2f(u0.w);
      if (b + 4 < cn) {
        int e1 = b + 4 + grp;
        float w1 = __shfl(swv, e1); int i1 = __shfl(si, e1);
        ushort4 u1 = ((const ushort4*)(yin + (size_t)i1 * 64))[q];
        a1.x += w1 * h2f(u1.x); a1.y += w1 * h2f(u1.y);
        a1.z += w1 * h2f(u1.z); a1.w += w1 * h2f(u1.w);
      }
      if (b + 8 < cn) {
        int e2 = b + 8 + grp;
        int e3 = b + 12 + grp;
        float w2 = __shfl(swv, e2); int i2 = __shfl(si, e2);
        float w3 = __shfl(swv, e3); int i3 = __shfl(si, e3);
        ushort4 u2 = ((const ushort4*)(yin + (size_t)i2 * 64))[q];
        ushort4 u3 = ((const ushort4*)(yin + (size_t)i3 * 64))[q];
        a2.x += w2 * h2f(u2.x); a2.y += w2 * h2f(u2.y);
        a2.z += w2 * h2f(u2.z); a2.w += w2 * h2f(u2.w);
        a3.x += w3 * h2f(u3.x); a3.y += w3 * h2f(u3.y);
        a3.z += w3 * h2f(u3.z); a3.w += w3 * h2f(u3.w);
      }
    }

    a0.x += a1.x + a2.x + a3.x;
    a0.y += a1.y + a2.y + a3.y;
    a0.z += a1.z + a2.z + a3.z;
    a0.w += a1.w + a2.w + a3.w;
#pragma unroll
    for (int d = 16; d <= 32; d <<= 1) {
      a0.x += __shfl_xor(a0.x, d);
      a0.y += __shfl_xor(a0.y, d);
      a0.z += __shfl_xor(a0.z, d);
      a0.w += __shfl_xor(a0.w, d);
    }

    if (grp == 0) {
      float sc = scale[v];
      float rx = sc * (a0.x + 2.0f * h2f(hvu[i].x));
      float ry = sc * (a0.y + 2.0f * h2f(hvu[i].y));
      float rz = sc * (a0.z + 2.0f * h2f(hvu[i].z));
      float rw = sc * (a0.w + 2.0f * h2f(hvu[i].w));
      ushort4 r;
      r.x = f2h(rx); r.y = f2h(ry); r.z = f2h(rz); r.w = f2h(rw);
      ((ushort4*)(yout + (size_t)v * 64))[q] = r;
      if (partc) {
        float wv = sq[v];
        cs.x += wv * rx; cs.y += wv * ry;
        cs.z += wv * rz; cs.w += wv * rw;
      }
    }
  }

  if (partc) {
    if (grp == 0) sdc[wave][q] = cs;
    __syncthreads();
    if (threadIdx.x < 16) {
      int qq = threadIdx.x;
      float4 a = sdc[0][qq], b = sdc[1][qq], c = sdc[2][qq], d = sdc[3][qq];
      a.x += b.x + c.x + d.x;
      a.y += b.y + c.y + d.y;
      a.z += b.z + c.z + d.z;
      a.w += b.w + c.w + d.w;
      ((float4*)(partc + (size_t)blockIdx.x * 64))[qq] = a;
    }
  }
}

// ---------------- contraction v4: LDS-staged, slab-level conversion ----------------
#define CT_BLOCKS 768
#define CT_NCHUNK ((N_NODES + 63) / 64)   // 1563

__global__ __launch_bounds__(256) void k_contract(
    const float* __restrict__ x0, const unsigned short* __restrict__ y3,
    float* __restrict__ part) {
  __shared__ __align__(16) float xs[64 * 128];   // 32 KB
  __shared__ __align__(16) float ysf[64 * 64];   // 16 KB converted f32
  int t = threadIdx.x;
  int w = t >> 6;
  int lane = t & 63;
  int j = lane * 2;

  float2 acc[16];
#pragma unroll
  for (int i = 0; i < 16; i++) acc[i] = make_float2(0.f, 0.f);

  for (int c = blockIdx.x; c < CT_NCHUNK; c += gridDim.x) {
    int cc = min(64, N_NODES - c * 64);
    int bx = cc * 512;
    int byh = cc * 128;
    const char* gx = (const char*)(x0 + (size_t)c * 64 * 128);
    const char* gy = (const char*)(y3 + (size_t)c * 64 * 64);
    __syncthreads();
#pragma unroll
    for (int i = 0; i < 8; i++) {
      int off = i * 4096 + t * 16;
      if (off < bx) GLOAD_LDS16(gx + off, (char*)xs + off);
    }
    ushort4 u[4];
#pragma unroll
    for (int r = 0; r < 4; r++) {
      int off = (r * 256 + t) * 8;
      u[r] = (off < byh) ? *(const ushort4*)(gy + off)
                         : make_ushort4(0, 0, 0, 0);
    }
#pragma unroll
    for (int r = 0; r < 4; r++) {
      int idx = (r * 256 + t) * 4;
      if (idx < cc * 64)
        *(float4*)(ysf + idx) = make_float4(h2f(u[r].x), h2f(u[r].y),
                                            h2f(u[r].z), h2f(u[r].w));
    }
    asm volatile("s_waitcnt vmcnt(0)" ::: "memory");
    __syncthreads();

    int v = 0;
    for (; v + 2 <= cc; v += 2) {
      float2 xa = *(const float2*)(xs + v * 128 + j);
      float2 xb = *(const float2*)(xs + (v + 1) * 128 + j);
      const float4* ya = (const float4*)(ysf + v * 64 + w * 16);
      const float4* yb = (const float4*)(ysf + (v + 1) * 64 + w * 16);
      float4 a0 = ya[0], a1 = ya[1], a2 = ya[2], a3 = ya[3];
      float4 b0 = yb[0], b1 = yb[1], b2 = yb[2], b3 = yb[3];
      float yas[16] = {a0.x, a0.y, a0.z, a0.w, a1.x, a1.y, a1.z, a1.w,
                       a2.x, a2.y, a2.z, a2.w, a3.x, a3.y, a3.z, a3.w};
      float ybs[16] = {b0.x, b0.y, b0.z, b0.w, b1.x, b1.y, b1.z, b1.w,
                       b2.x, b2.y, b2.z, b2.w, b3.x, b3.y, b3.z, b3.w};
#pragma unroll
      for (int i = 0; i < 16; i++) {
        acc[i].x += yas[i] * xa.x;
        acc[i].y += yas[i] * xa.y;
      }
#pragma unroll
      for (int i = 0; i < 16; i++) {
        acc[i].x += ybs[i] * xb.x;
        acc[i].y += ybs[i] * xb.y;
      }
    }
    if (v < cc) {
      float2 xa = *(const float2*)(xs + v * 128 + j);
      const float4* ya = (const float4*)(ysf + v * 64 + w * 16);
      float4 a0 = ya[0], a1 = ya[1], a2 = ya[2], a3 = ya[3];
      float yas[16] = {a0.x, a0.y, a0.z, a0.w, a1.x, a1.y, a1.z, a1.w,
                       a2.x, a2.y, a2.z, a2.w, a3.x, a3.y, a3.z, a3.w};
#pragma unroll
      for (int i = 0; i < 16; i++) {
        acc[i].x += yas[i] * xa.x;
        acc[i].y += yas[i] * xa.y;
      }
    }
  }

  float* dst = part + (size_t)blockIdx.x * (N_GRAPHS * WIDTH);
#pragma unroll
  for (int i = 0; i < 16; i++)
    *(float2*)(dst + (w * 16 + i) * WIDTH + j) = acc[i];
}

// ---------------- partials reduction: 768 rows -> 12 rows ----------------
#define RC_ROWS 64
#define RC_RG (CT_BLOCKS / RC_ROWS)   // 12

__global__ __launch_bounds__(256) void k_reduce1(
    const float* __restrict__ part, float* __restrict__ part2) {
  int bid = blockIdx.x, t = threadIdx.x;
  int rg = bid >> 5, colc = bid & 31;
  int idx = colc * 256 + t;
  const float* src = part + (size_t)rg * RC_ROWS * (N_GRAPHS * WIDTH) + idx;
  float a0 = 0.f, a1 = 0.f, a2 = 0.f, a3 = 0.f;
  for (int r = 0; r < RC_ROWS; r += 4) {
    a0 += src[(size_t)(r + 0) * (N_GRAPHS * WIDTH)];
    a1 += src[(size_t)(r + 1) * (N_GRAPHS * WIDTH)];
    a2 += src[(size_t)(r + 2) * (N_GRAPHS * WIDTH)];
    a3 += src[(size_t)(r + 3) * (N_GRAPHS * WIDTH)];
  }
  part2[rg * (N_GRAPHS * WIDTH) + idx] = (a0 + a1) + (a2 + a3);
}

// O = A*B (128x128 f32); block=row, thread=col
__global__ __launch_bounds__(WIDTH) void k_mm128(
    const float* __restrict__ A, const float* __restrict__ B, float* __restrict__ O) {
  __shared__ float Ar[WIDTH];
  int r = blockIdx.x, j = threadIdx.x;
  Ar[j] = A[r * WIDTH + j];
  __syncthreads();
  float a = 0.f;
#pragma unroll 8
  for (int k = 0; k < WIDTH; k++) a += Ar[k] * B[k * WIDTH + j];
  O[r * WIDTH + j] = a;
}

// c0 = b0^T * T1 ; c1 = b1^T * W2
__global__ __launch_bounds__(WIDTH) void k_c01(
    const float* __restrict__ b0, const float* __restrict__ T1,
    const float* __restrict__ b1, const float* __restrict__ W2,
    float* __restrict__ c0, float* __restrict__ c1) {
  __shared__ float s0[WIDTH], s1v[WIDTH];
  int j = threadIdx.x;
  s0[j] = b0[j]; s1v[j] = b1[j];
  __syncthreads();
  float a0 = 0.f, a1 = 0.f;
#pragma unroll 8
  for (int k = 0; k < WIDTH; k++) {
    a0 += s0[k] * T1[k * WIDTH + j];
    a1 += s1v[k] * W2[k * WIDTH + j];
  }
  c0[j] = a0; c1[j] = a1;
}

// out[g][j]: final 12-row C-sum + 64-row ps/pas reduction fused in.
__global__ __launch_bounds__(WIDTH) void k_out(
    const float* __restrict__ part2, const float* __restrict__ Wp,
    const float* __restrict__ c0, const float* __restrict__ c1,
    const float* __restrict__ part3, const int* __restrict__ cntg,
    const float* __restrict__ b2, float* __restrict__ out) {
  __shared__ float Cr[WIDTH];
  __shared__ float sa[64], sb[64];
  int g = blockIdx.x, j = threadIdx.x;
  // ps/pas: reduce 64 chunk-partials each (csA -> part3[0], csB -> part3[1])
  if (j < 64) sa[j] = part3[(size_t)j * 64 + g];
  else        sb[j - 64] = part3[(size_t)(64 + (j - 64)) * 64 + g];
  float cv = 0.f;
#pragma unroll
  for (int rg = 0; rg < RC_RG; rg++)
    cv += part2[rg * (N_GRAPHS * WIDTH) + g * WIDTH + j];
  Cr[j] = cv;
  __syncthreads();
#pragma unroll
  for (int off = 32; off > 0; off >>= 1) {
    if (j < off) sa[j] += sa[j + off];
    else if (j >= 64 && (j - 64) < off) sb[j - 64] += sb[j - 64 + off];
    __syncthreads();
  }
  float ps_g = sa[0], pas_g = sb[0];
  float a = pas_g * c0[j] + ps_g * c1[j] + ((cntg[g] > 0) ? b2[j] : 0.f);
#pragma unroll 8
  for (int k = 0; k < WIDTH; k++) a += Cr[k] * Wp[k * WIDTH + j];
  out[g * WIDTH + j] = a;
}

// ---------------- launch ----------------

extern "C" void kernel_launch(void* const* d_in, const int* in_sizes, int n_in,
                              void* d_out, int out_size, void* d_ws, size_t ws_size,
                              hipStream_t stream) {
  const float* x   = (const float*)d_in[0];
  const int* row   = (const int*)d_in[1];         // edge_index[0]
  const int* col   = row + N_EDGES;               // edge_index[1]
  const float* ew  = (const float*)d_in[2];
  const int* batch = (const int*)d_in[3];
  const float* Ws  = (const float*)d_in[4];
  const float* bs  = (const float*)d_in[5];
  float* out = (float*)d_out;

  char* w = (char*)d_ws;
  float* dinv    = (float*)(w + 0);
  float* d2      = (float*)(w + 400128);
  float* sq      = (float*)(w + 800256);
  float* deg     = (float*)(w + 1200384);
  int*   cursor  = (int*)(w + 1600512);
  int*   cntg    = (int*)(w + 2000640);
  float* invc    = (float*)(w + 2000896);
  float* T1      = (float*)(w + 2001664);
  float* Wp      = (float*)(w + 2067200);
  float* c0      = (float*)(w + 2132736);
  float* c1      = (float*)(w + 2133248);
  int2*  ell     = (int2*)(w + 2133760);     // 32 MB -> ends 34133760
  float* part    = (float*)(w + 34133760);   // 768*8192*4 = 25.2 MB
  float* part2   = (float*)(w + 67688192);   // 12*8192*4
  unsigned short* yA = (unsigned short*)(w + 68212480);  // N*64 fp16
  unsigned short* yB = (unsigned short*)(w + 81012480);  // N*64 fp16, ends 93812480
  float* csA     = (float*)(w + 93812480);   // 6250*64 f32 = 1.6MB
  float* csB     = (float*)(w + 95412480);   // ends 97012480
  float* part3   = (float*)(w + 97012480);   // 2*64*64 f32 = 32KB

  int nb_n = (N_NODES + 255) / 256;
  int nb_e = (N_EDGES + 255) / 256;

  k_init   <<<nb_n, 256, 0, stream>>>(cursor, deg);
  k_fill_cd<<<nb_e, 256, 0, stream>>>(row, col, ew, cursor, deg, ell);
  k_dinv_e <<<nb_n, 256, 0, stream>>>(deg, dinv, d2, sq);

  k_cntg <<<1, 64, 0, stream>>>(batch, cntg, invc);
  k_pinit<<<2048, 256, 0, stream>>>(batch, invc, dinv, yA);

  k_yagg<<<YBLK, 256, 0, stream>>>(yA, cursor, ell, d2, sq, yB, csA);      // z1 (+ps)
  k_yagg<<<YBLK, 256, 0, stream>>>(yB, cursor, ell, d2, sq, yA, csB);      // z2 (+pas)
  k_yagg<<<YBLK, 256, 0, stream>>>(yA, cursor, ell, dinv, sq, yB, nullptr);// y3

  k_csr  <<<128, 256, 0, stream>>>(csA, csB, part3);
  k_mm128<<<WIDTH, WIDTH, 0, stream>>>(Ws + 1 * WIDTH * WIDTH, Ws + 2 * WIDTH * WIDTH, T1);
  k_mm128<<<WIDTH, WIDTH, 0, stream>>>(Ws + 0 * WIDTH * WIDTH, T1, Wp);
  k_c01  <<<1, WIDTH, 0, stream>>>(bs, T1, bs + WIDTH, Ws + 2 * WIDTH * WIDTH, c0, c1);

  k_contract<<<CT_BLOCKS, 256, 0, stream>>>(x, yB, part);
  k_reduce1 <<<RC_RG * 32, 256, 0, stream>>>(part, part2);
  k_out     <<<N_GRAPHS, WIDTH, 0, stream>>>(part2, Wp, c0, c1, part3, cntg,
                                             bs + 2 * WIDTH, out);
}